// Round 5
// baseline (539.159 us; speedup 1.0000x reference)
//
#include <hip/hip_runtime.h>
#include <hip/hip_bf16.h>

// StructuralEncoder: gather(3x128 f32) -> 384->256->256->128 MLP (relu,relu,linear)
// -> mean over 1M rows -> 128->256->128 head.
// R5: switch to mfma_f32_32x32x16_bf16 (4061 FLOP/cy vs 3378, half the MFMA
// instruction count), keep R4's 48KB in-place LDS / 5 barriers / 3 blocks/CU.
// Single fused prep kernel (pack all weights + zero partials).

#define EMBED 128
#define BM 64
#define NBUCKET 128

typedef __bf16 bf16x8 __attribute__((ext_vector_type(8)));
typedef __bf16 bf16x4 __attribute__((ext_vector_type(4)));
typedef float f32x4 __attribute__((ext_vector_type(4)));
typedef float f32x16 __attribute__((ext_vector_type(16)));

// pack W (K x N row-major) into 32(feature)x16(k) A-frag tiles for 32x32x16:
// dst[((mt*(K/16)+kt)*64 + l)*8 + j] = W[(kt*16+(l>>5)*8+j)*N + (mt*32+(l&31))]
// Also zeroes the partial-sum buckets. W1:384x256 W2:256x256 W3:256x128.
__global__ void prep_all(const float* __restrict__ W1, const float* __restrict__ W2,
                         const float* __restrict__ W3,
                         __bf16* __restrict__ W1p, __bf16* __restrict__ W2p,
                         __bf16* __restrict__ W3p, float* __restrict__ prt) {
    int idx = blockIdx.x * 256 + threadIdx.x;
    if (idx < NBUCKET * 128) prt[idx] = 0.f;
    const float* src; __bf16* dst; int K, N, e;
    if (idx < 98304)       { src = W1; dst = W1p; K = 384; N = 256; e = idx; }
    else if (idx < 163840) { src = W2; dst = W2p; K = 256; N = 256; e = idx - 98304; }
    else if (idx < 196608) { src = W3; dst = W3p; K = 256; N = 128; e = idx - 163840; }
    else return;
    int j = e & 7, l = (e >> 3) & 63, t = e >> 9;
    int KT = K >> 4;
    int kt = t % KT, mt = t / KT;
    int k  = kt * 16 + (l >> 5) * 8 + j;
    int nc = mt * 32 + (l & 31);
    dst[e] = (__bf16)src[k * N + nc];
}

// ---- main fused MLP over 64-row tiles ----
__global__ __launch_bounds__(256, 3) void mlp_main(
    const int* __restrict__ triples,
    const float* __restrict__ ent, const float* __restrict__ rel,
    const __bf16* __restrict__ W1p, const float* __restrict__ b1,
    const __bf16* __restrict__ W2p, const float* __restrict__ b2,
    const __bf16* __restrict__ W3p,
    float* __restrict__ part, int n)
{
    // LDS 48KB, time-multiplexed (R4 scheme):
    //   phase 1: xs  [0,48K) = 64 rows x 768B (384 bf16), 16B-chunk swizzle
    //   phase 2: h1s [0,32K) = 64 x 512B (after B2)
    //   phase 3: h2s [0,32K) = 64 x 512B (after B4)
    __shared__ unsigned char lds[49152];
    unsigned char* xs  = lds;
    unsigned char* h1s = lds;
    unsigned char* h2s = lds;

    const int tid  = threadIdx.x;
    const int wave = tid >> 6;
    const int lane = tid & 63;
    const int l31  = lane & 31;
    const int hi   = lane >> 5;          // 0/1: k-half for A/B frags, feature+4 for C/D
    const int swzB = (l31 & 7) << 4;     // B-frag row swizzle (row = nn*32+l31; &7 == l31&7)
    const int s0   = blockIdx.x * BM;
    const int sp   = tid >> 4;           // sample subgroup for staging
    const int ch   = tid & 15;           // 16B bf16 chunk within a c-row

    // ---- prologue: triple indices, then issue ALL gather loads ----
    int rows[3][4];
#pragma unroll
    for (int p = 0; p < 4; p++) {
        int g = s0 + p * 16 + sp;
        const int* t = triples + (g < n ? g : 0) * 3;
        rows[0][p] = t[0]; rows[1][p] = t[1]; rows[2][p] = t[2];
    }
    float4 ga[3][4], gb[3][4];
#pragma unroll
    for (int c = 0; c < 3; c++) {
        const float* tbl = (c == 1) ? rel : ent;
#pragma unroll
        for (int p = 0; p < 4; p++) {
            const float* src = tbl + (long)rows[c][p] * EMBED + ch * 8;
            ga[c][p] = *(const float4*)src;
            gb[c][p] = *(const float4*)(src + 4);
        }
    }
    // cvt + write xs (row s: [e1|rel|e2], 768B, 16B-chunk XOR swizzle)
#pragma unroll
    for (int c = 0; c < 3; c++)
#pragma unroll
        for (int p = 0; p < 4; p++) {
            bf16x8 w;
            w[0] = (__bf16)ga[c][p].x; w[1] = (__bf16)ga[c][p].y;
            w[2] = (__bf16)ga[c][p].z; w[3] = (__bf16)ga[c][p].w;
            w[4] = (__bf16)gb[c][p].x; w[5] = (__bf16)gb[c][p].y;
            w[6] = (__bf16)gb[c][p].z; w[7] = (__bf16)gb[c][p].w;
            int s = p * 16 + sp;
            int off = (s * 768 + c * 256 + ch * 16) ^ ((s & 7) << 4);
            *(bf16x8*)(xs + off) = w;
        }
    __syncthreads();  // B1: xs ready

    // ========== Layer 1: h1 = relu(x @ W1 + b1), K=384 (24 k-steps) ==========
    // wave owns features [wave*64, wave*64+64) = 2 m-frags of 32
    f32x16 acc[2][2];
#pragma unroll
    for (int m = 0; m < 2; m++)
#pragma unroll
        for (int g = 0; g < 4; g++) {
            f32x4 bb = *(const f32x4*)(b1 + wave * 64 + m * 32 + g * 8 + hi * 4);
#pragma unroll
            for (int nn = 0; nn < 2; nn++)
#pragma unroll
                for (int j = 0; j < 4; j++) acc[m][nn][g * 4 + j] = bb[j];
        }
    __builtin_amdgcn_s_setprio(1);
#pragma unroll
    for (int kk = 0; kk < 24; kk++) {
        bf16x8 bfr[2];
#pragma unroll
        for (int nn = 0; nn < 2; nn++) {
            int s = nn * 32 + l31;
            bfr[nn] = *(const bf16x8*)(xs + ((s * 768 + kk * 32 + hi * 16) ^ swzB));
        }
        bf16x8 afr[2];
#pragma unroll
        for (int m = 0; m < 2; m++)
            afr[m] = *(const bf16x8*)(W1p + ((wave * 2 + m) * 24 + kk) * 512 + lane * 8);
#pragma unroll
        for (int m = 0; m < 2; m++)
#pragma unroll
            for (int nn = 0; nn < 2; nn++)
                acc[m][nn] = __builtin_amdgcn_mfma_f32_32x32x16_bf16(
                    afr[m], bfr[nn], acc[m][nn], 0, 0, 0);
    }
    __builtin_amdgcn_s_setprio(0);
    __syncthreads();  // B2: all xs reads done; h1 may overwrite region
    // write h1 (relu, bf16): feature = wave*64+m*32+(g*8+hi*4)+j', sample s
#pragma unroll
    for (int m = 0; m < 2; m++)
#pragma unroll
        for (int nn = 0; nn < 2; nn++) {
            int s = nn * 32 + l31;
#pragma unroll
            for (int g = 0; g < 4; g++) {
                int f0 = wave * 64 + m * 32 + g * 8 + hi * 4;
                bf16x4 p;
#pragma unroll
                for (int j = 0; j < 4; j++) {
                    float v = acc[m][nn][g * 4 + j];
                    p[j] = (__bf16)(v > 0.f ? v : 0.f);
                }
                *(bf16x4*)(h1s + ((s * 512 + f0 * 2) ^ ((s & 7) << 4))) = p;
            }
        }
    __syncthreads();  // B3: h1 ready

    // ========== Layer 2: h2 = relu(h1 @ W2 + b2), K=256 (16 k-steps) ==========
    f32x16 acc2[2][2];
#pragma unroll
    for (int m = 0; m < 2; m++)
#pragma unroll
        for (int g = 0; g < 4; g++) {
            f32x4 bb = *(const f32x4*)(b2 + wave * 64 + m * 32 + g * 8 + hi * 4);
#pragma unroll
            for (int nn = 0; nn < 2; nn++)
#pragma unroll
                for (int j = 0; j < 4; j++) acc2[m][nn][g * 4 + j] = bb[j];
        }
    __builtin_amdgcn_s_setprio(1);
#pragma unroll
    for (int kk = 0; kk < 16; kk++) {
        bf16x8 bfr[2];
#pragma unroll
        for (int nn = 0; nn < 2; nn++) {
            int s = nn * 32 + l31;
            bfr[nn] = *(const bf16x8*)(h1s + ((s * 512 + kk * 32 + hi * 16) ^ swzB));
        }
        bf16x8 afr[2];
#pragma unroll
        for (int m = 0; m < 2; m++)
            afr[m] = *(const bf16x8*)(W2p + ((wave * 2 + m) * 16 + kk) * 512 + lane * 8);
#pragma unroll
        for (int m = 0; m < 2; m++)
#pragma unroll
            for (int nn = 0; nn < 2; nn++)
                acc2[m][nn] = __builtin_amdgcn_mfma_f32_32x32x16_bf16(
                    afr[m], bfr[nn], acc2[m][nn], 0, 0, 0);
    }
    __builtin_amdgcn_s_setprio(0);
    __syncthreads();  // B4: all h1 reads done; h2 may overwrite region
#pragma unroll
    for (int m = 0; m < 2; m++)
#pragma unroll
        for (int nn = 0; nn < 2; nn++) {
            int s = nn * 32 + l31;
#pragma unroll
            for (int g = 0; g < 4; g++) {
                int f0 = wave * 64 + m * 32 + g * 8 + hi * 4;
                bf16x4 p;
#pragma unroll
                for (int j = 0; j < 4; j++) {
                    float v = acc2[m][nn][g * 4 + j];
                    p[j] = (__bf16)(v > 0.f ? v : 0.f);
                }
                *(bf16x4*)(h2s + ((s * 512 + f0 * 2) ^ ((s & 7) << 4))) = p;
            }
        }
    __syncthreads();  // B5: h2 ready

    // ========== Layer 3: enc = h2 @ W3 (bias in head), K=256 ==========
    // 128 output features = 4 frags of 32; wave owns frag `wave`
    f32x16 acc3[2];
#pragma unroll
    for (int nn = 0; nn < 2; nn++)
#pragma unroll
        for (int j = 0; j < 16; j++) acc3[nn][j] = 0.f;
    __builtin_amdgcn_s_setprio(1);
#pragma unroll
    for (int kk = 0; kk < 16; kk++) {
        bf16x8 afr = *(const bf16x8*)(W3p + (wave * 16 + kk) * 512 + lane * 8);
#pragma unroll
        for (int nn = 0; nn < 2; nn++) {
            int s = nn * 32 + l31;
            bf16x8 bfr = *(const bf16x8*)(h2s + ((s * 512 + kk * 32 + hi * 16) ^ swzB));
            acc3[nn] = __builtin_amdgcn_mfma_f32_32x32x16_bf16(
                afr, bfr, acc3[nn], 0, 0, 0);
        }
    }
    __builtin_amdgcn_s_setprio(0);
    // reduce over samples, accumulate into bucket
    // value(f,s): f = wave*32 + (r&3) + 8*(r>>2) + hi*4, s = nn*32 + l31
    {
        float* bucket = part + (blockIdx.x & (NBUCKET - 1)) * 128;
#pragma unroll
        for (int r = 0; r < 16; r++) {
            float v = 0.f;
#pragma unroll
            for (int nn = 0; nn < 2; nn++) {
                int g = s0 + nn * 32 + l31;
                float t = acc3[nn][r];
                v += (g < n) ? t : 0.f;
            }
            v += __shfl_xor(v, 1);
            v += __shfl_xor(v, 2);
            v += __shfl_xor(v, 4);
            v += __shfl_xor(v, 8);
            v += __shfl_xor(v, 16);
            if (l31 == 0) {
                int f = wave * 32 + (r & 3) + 8 * (r >> 2) + hi * 4;
                atomicAdd(bucket + f, v);
            }
        }
    }
}

// ---- head: agg = sum/n + b3; out = relu(agg@Wf1+bf1)@Wf2+bf2 (f32) ----
__global__ void head_kernel(const float* __restrict__ part, const float* __restrict__ b3,
                            const float* __restrict__ Wf1, const float* __restrict__ bf1,
                            const float* __restrict__ Wf2, const float* __restrict__ bf2,
                            float* __restrict__ out, int n)
{
    __shared__ float agg[128];
    __shared__ float t[256];
    const int tid = threadIdx.x;
    if (tid < 128) {
        float s = 0.f;
        for (int b = 0; b < NBUCKET; b++) s += part[b * 128 + tid];
        agg[tid] = s / (float)n + b3[tid];
    }
    __syncthreads();
    {
        float a = bf1[tid];
        for (int k = 0; k < 128; k++) a += agg[k] * Wf1[k * 256 + tid];
        t[tid] = a > 0.f ? a : 0.f;
    }
    __syncthreads();
    if (tid < 128) {
        float o = bf2[tid];
        for (int i = 0; i < 256; i++) o += t[i] * Wf2[i * 128 + tid];
        out[tid] = o;
    }
}

extern "C" void kernel_launch(void* const* d_in, const int* in_sizes, int n_in,
                              void* d_out, int out_size, void* d_ws, size_t ws_size,
                              hipStream_t stream) {
    const int*   triples = (const int*)d_in[0];
    const float* ent     = (const float*)d_in[1];
    const float* rel     = (const float*)d_in[2];
    const float* W1      = (const float*)d_in[3];
    const float* b1      = (const float*)d_in[4];
    const float* W2      = (const float*)d_in[5];
    const float* b2      = (const float*)d_in[6];
    const float* W3      = (const float*)d_in[7];
    const float* b3      = (const float*)d_in[8];
    const float* Wf1     = (const float*)d_in[9];
    const float* bf1     = (const float*)d_in[10];
    const float* Wf2     = (const float*)d_in[11];
    const float* bf2     = (const float*)d_in[12];
    float* out = (float*)d_out;
    const int n = in_sizes[0] / 3;

    // ws layout (bytes): W1p[0,196608) W2p[196608,327680) W3p[327680,393216)
    //                    part[393216,458752)
    __bf16* W1p = (__bf16*)d_ws;
    __bf16* W2p = (__bf16*)((char*)d_ws + 196608);
    __bf16* W3p = (__bf16*)((char*)d_ws + 327680);
    float*  prt = (float*)((char*)d_ws + 393216);

    prep_all<<<768, 256, 0, stream>>>(W1, W2, W3, W1p, W2p, W3p, prt);

    const int blocks = (n + BM - 1) / BM;
    mlp_main<<<blocks, 256, 0, stream>>>(triples, ent, rel, W1p, b1, W2p, b2, W3p, prt, n);
    head_kernel<<<1, 256, 0, stream>>>(prt, b3, Wf1, bf1, Wf2, bf2, out, n);
}